// Round 2
// baseline (102162.524 us; speedup 1.0000x reference)
//
#include <hip/hip_runtime.h>
#include <hip/hip_bf16.h>
#include <cstddef>

#define B_ 128
#define T_ 256
#define H_ 512
#define H4_ 2048

__device__ __forceinline__ float rcp_f(float x) { return __builtin_amdgcn_rcpf(x); }
__device__ __forceinline__ float sigf(float x) { return rcp_f(1.0f + __expf(-x)); }
__device__ __forceinline__ float tanh_f(float x) {
  float p = __expf(x + x);                    // e^{2x}
  return fmaf(-2.0f, rcp_f(1.0f + p), 1.0f);  // 1 - 2/(1+e^{2x})
}
__device__ __forceinline__ float4 ld4(const float* p) { return *reinterpret_cast<const float4*>(p); }
__device__ __forceinline__ void st4(float* p, float4 v) { *reinterpret_cast<float4*>(p) = v; }
__device__ __forceinline__ void fma4(float4& a, float s, float4 w) {
  a.x = fmaf(s, w.x, a.x); a.y = fmaf(s, w.y, a.y);
  a.z = fmaf(s, w.z, a.z); a.w = fmaf(s, w.w, a.w);
}

// ---------------- workspace layout (floats) ----------------
#define W1E_OFF    0ull            // 16777216
#define WPACK_OFF  16777216ull     // 1572864   Wpack[g][k=768][c=8]
#define W2PACK_OFF 18350080ull     // 262144    W2pack[g][k=512][jj=2]
#define HP_OFF     18612224ull     // 131072 = 2 x (256 jh2 x 128 b x 2) transposed h
#define EP_OFF     18743296ull     // 32768  = 128 t2 x 128 b x 2  transposed e
#define W2D_OFF    18776064ull     // 65536  = [b][512]
#define D2_OFF     18841600ull     // 512 = 2 x [b][2]
#define CNT_OFF    18842112ull     // 512 uints (32 counters, 64B stride)

// ---------------- w1e = enc[32768,512] @ W1[512,512] (fp32, 64x64 tile) ----------------
__global__ __launch_bounds__(256) void w1e_kernel(const float* __restrict__ A,
                                                  const float* __restrict__ Bw,
                                                  float* __restrict__ C) {
  __shared__ float As[32][68];
  __shared__ float Bs[32][68];
  const int i0 = blockIdx.x * 64;
  const int j0 = blockIdx.y * 64;
  const int tx = threadIdx.x & 15, ty = threadIdx.x >> 4;
  float4 acc0 = make_float4(0,0,0,0), acc1 = acc0, acc2 = acc0, acc3 = acc0;
  for (int k0 = 0; k0 < H_; k0 += 32) {
#pragma unroll
    for (int q = 0; q < 2; q++) {
      int idx = q * 256 + threadIdx.x;
      int ai = idx >> 3, ak = (idx & 7) << 2;
      float4 av = ld4(A + (size_t)(i0 + ai) * H_ + k0 + ak);
      As[ak][ai] = av.x; As[ak + 1][ai] = av.y; As[ak + 2][ai] = av.z; As[ak + 3][ai] = av.w;
      int bk = idx >> 4, bj = (idx & 15) << 2;
      st4(&Bs[bk][bj], ld4(Bw + (size_t)(k0 + bk) * H_ + j0 + bj));
    }
    __syncthreads();
#pragma unroll
    for (int kk = 0; kk < 32; kk++) {
      float4 a = ld4(&As[kk][ty << 2]);
      float4 bv = ld4(&Bs[kk][tx << 2]);
      fma4(acc0, a.x, bv); fma4(acc1, a.y, bv); fma4(acc2, a.z, bv); fma4(acc3, a.w, bv);
    }
    __syncthreads();
  }
  size_t base = (size_t)(i0 + (ty << 2)) * H_ + j0 + (tx << 2);
  st4(&C[base], acc0); st4(&C[base + H_], acc1);
  st4(&C[base + 2 * H_], acc2); st4(&C[base + 3 * H_], acc3);
}

// ---------------- pack weights per-WG contiguous + zero barrier counters ----------------
__global__ __launch_bounds__(256) void pack_kernel(const float* __restrict__ Wk,
                                                   const float* __restrict__ Wr,
                                                   const float* __restrict__ W2,
                                                   float* __restrict__ Wpack,
                                                   float* __restrict__ W2pack,
                                                   unsigned* __restrict__ cnt) {
  const int g = blockIdx.x, tid = threadIdx.x;
#pragma unroll
  for (int it = 0; it < 24; ++it) {
    int idx = it * 256 + tid;            // 0..6143
    int k = idx >> 3, c = idx & 7;       // c = gate*2 + jj
    int col = (c >> 1) * 512 + 2 * g + (c & 1);
    float v = (k < 256) ? Wk[(size_t)k * H4_ + col] : Wr[(size_t)(k - 256) * H4_ + col];
    Wpack[((size_t)g * 768 + k) * 8 + c] = v;
  }
#pragma unroll
  for (int it = 0; it < 4; ++it) {
    int idx = it * 256 + tid;            // 0..1023
    int k = idx >> 1, jj = idx & 1;
    W2pack[((size_t)g * 512 + k) * 2 + jj] = W2[(size_t)k * H_ + 2 * g + jj];
  }
  if (g == 0 && tid < 512) cnt[tid] = 0u;
}

// ---------------- grid barrier: 32 counters (64B apart), monotonic targets ----------------
__device__ __forceinline__ void gridbar(unsigned* cnt, unsigned& tgt, int tid) {
  tgt += 8;  // 8 WGs feed each of the 32 counters
  __threadfence();
  __syncthreads();
  if (tid < 64) {
    if (tid == 0)
      __hip_atomic_fetch_add(&cnt[(blockIdx.x & 31) * 16], 1u,
                             __ATOMIC_RELAXED, __HIP_MEMORY_SCOPE_AGENT);
    const unsigned* myc = &cnt[(tid & 31) * 16];
    for (;;) {
      unsigned v = __hip_atomic_load(myc, __ATOMIC_RELAXED, __HIP_MEMORY_SCOPE_AGENT);
      if (__all((int)(v >= tgt))) break;
      __builtin_amdgcn_s_sleep(1);
    }
  }
  __threadfence();
  __syncthreads();
}

// ---------------- persistent decoder: 256 WGs x 1024 thr, 1 WG/CU ----------------
__global__ __launch_bounds__(1024, 4) void decoder_persistent(
    const float* __restrict__ w1e, const float* __restrict__ Wpack,
    const float* __restrict__ W2pack, const float* __restrict__ Vv,
    const float* __restrict__ bias, const float* __restrict__ h0,
    const float* __restrict__ c0,
    float* __restrict__ hp,    // [2][256][128][2]
    float* __restrict__ ep,    // [128][128][2]
    float* __restrict__ w2d,   // [128][512]
    float* __restrict__ d2,    // [2][128][2]
    unsigned* __restrict__ cnt,
    float* __restrict__ out) {
  // 84KB LDS: forces exactly 1 WG per CU -> all 256 WGs co-resident (barrier-safe)
  __shared__ float smem[21504];
  float* zred     = smem;            // [8][128][12] = 12288
  float* zfin     = smem + 12288;    // [128][8]     = 1024
  float* c_lds    = smem + 13312;    // [128][2]     = 256
  float* bias_lds = smem + 13568;    // [8]
  float* dred     = smem + 13576;    // [16]

  const int g = blockIdx.x;
  const int tid = threadIdx.x;
  const int bl = tid & 127;
  const int ksu = __builtin_amdgcn_readfirstlane(tid >> 7);  // wave-uniform k-split id 0..7
  unsigned tgt = 0;

  // ---- init: c-state, bias slice, h(-1) transposed, e(-1)=1, d(-1)=1 ----
  if (tid < 256) {
    int b = tid >> 1, jj = tid & 1;
    c_lds[b * 2 + jj] = c0[(size_t)b * H_ + 2 * g + jj];
    hp[65536 + ((size_t)g * 128 + b) * 2 + jj] = h0[(size_t)b * H_ + 2 * g + jj];
    if (g == 0) d2[256 + tid] = 0.5f;  // buffer 1: d(-1); pair sums to 1
  }
  if (tid < 8) bias_lds[tid] = bias[(tid >> 1) * 512 + 2 * g + (tid & 1)];
  if (g < 128 && tid < 128)
    ((float2*)ep)[g * 128 + tid] = make_float2(1.0f, 1.0f);
  gridbar(cnt, tgt, tid);

  // score-phase constants
  const int sb = g >> 1;            // batch row this WG scores
  const int t0 = (g & 1) << 7;      // t half
  const int wv = tid >> 6, ln = tid & 63;
  const float4 v0 = ld4(Vv + ln * 8), v1 = ld4(Vv + ln * 8 + 4);

  const float2* ep2 = (const float2*)ep;

  for (int s = 0; s < 256; ++s) {
    const float2* hin = (const float2*)(hp + ((s + 1) & 1) * 65536);
    float2* hout = (float2*)(hp + (s & 1) * 65536);
    const float2* d2r = (const float2*)(d2 + ((s + 1) & 1) * 256);
    float* d2w = d2 + (s & 1) * 256;

    // ================= gates =================
    {
      float2 dd = d2r[bl];
      float rd = rcp_f(dd.x + dd.y);
      float4 accA = make_float4(0,0,0,0), accB = accA;
      // e-part: k = ksu*4 + 32j + kk, covers [0,256)
#pragma unroll 2
      for (int j = 0; j < 8; ++j) {
        int kb = ksu * 4 + j * 32;
        float2 i0 = ep2[(kb >> 1) * 128 + bl];
        float2 i1 = ep2[(kb >> 1) * 128 + 128 + bl];
        const float* wp = Wpack + (((size_t)g * 768 + kb) << 3);
        float4 wa0 = ld4(wp),      wb0 = ld4(wp + 4);
        float4 wa1 = ld4(wp + 8),  wb1 = ld4(wp + 12);
        float4 wa2 = ld4(wp + 16), wb2 = ld4(wp + 20);
        float4 wa3 = ld4(wp + 24), wb3 = ld4(wp + 28);
        fma4(accA, i0.x, wa0); fma4(accB, i0.x, wb0);
        fma4(accA, i0.y, wa1); fma4(accB, i0.y, wb1);
        fma4(accA, i1.x, wa2); fma4(accB, i1.x, wb2);
        fma4(accA, i1.y, wa3); fma4(accB, i1.y, wb3);
      }
      accA.x *= rd; accA.y *= rd; accA.z *= rd; accA.w *= rd;
      accB.x *= rd; accB.y *= rd; accB.z *= rd; accB.w *= rd;
      // h-part: k-256 covers [0,512)
#pragma unroll 2
      for (int j = 0; j < 16; ++j) {
        int kb = ksu * 4 + j * 32;
        float2 i0 = hin[(kb >> 1) * 128 + bl];
        float2 i1 = hin[(kb >> 1) * 128 + 128 + bl];
        const float* wp = Wpack + (((size_t)g * 768 + 256 + kb) << 3);
        float4 wa0 = ld4(wp),      wb0 = ld4(wp + 4);
        float4 wa1 = ld4(wp + 8),  wb1 = ld4(wp + 12);
        float4 wa2 = ld4(wp + 16), wb2 = ld4(wp + 20);
        float4 wa3 = ld4(wp + 24), wb3 = ld4(wp + 28);
        fma4(accA, i0.x, wa0); fma4(accB, i0.x, wb0);
        fma4(accA, i0.y, wa1); fma4(accB, i0.y, wb1);
        fma4(accA, i1.x, wa2); fma4(accB, i1.x, wb2);
        fma4(accA, i1.y, wa3); fma4(accB, i1.y, wb3);
      }
      float* zr = &zred[(ksu * 128 + bl) * 12];
      st4(zr, accA); st4(zr + 4, accB);
    }
    __syncthreads();
    {  // k-split reduction: 1024 thr = 128 b x 8 c
      int b = tid >> 3, cc = tid & 7;
      float zsum = bias_lds[cc];
#pragma unroll
      for (int k = 0; k < 8; ++k) zsum += zred[(k * 128 + b) * 12 + cc];
      zfin[b * 8 + cc] = zsum;
    }
    __syncthreads();
    if (tid < 256) {  // LSTM epilogue for this WG's 2 h-cols
      int b = tid >> 1, jj = tid & 1;
      float zi = zfin[b * 8 + 0 + jj], zf = zfin[b * 8 + 2 + jj];
      float zg = zfin[b * 8 + 4 + jj], zo = zfin[b * 8 + 6 + jj];
      float cv = c_lds[b * 2 + jj];
      float cn = sigf(zf) * cv + sigf(zi) * tanh_f(zg);
      float hn = sigf(zo) * tanh_f(cn);
      c_lds[b * 2 + jj] = cn;
      ((float*)hout)[((size_t)g * 128 + b) * 2 + jj] = hn;
    }
    gridbar(cnt, tgt, tid);

    // ================= w2d =================
    {
      float2 a2 = make_float2(0.0f, 0.0f);
#pragma unroll 2
      for (int j = 0; j < 16; ++j) {
        int kb = ksu * 4 + j * 32;
        float2 h0v = hout[(kb >> 1) * 128 + bl];
        float2 h1v = hout[(kb >> 1) * 128 + 128 + bl];
        const float* wp = W2pack + (((size_t)g * 512 + kb) << 1);
        float4 w01 = ld4(wp), w23 = ld4(wp + 4);
        a2.x = fmaf(h0v.x, w01.x, a2.x); a2.y = fmaf(h0v.x, w01.y, a2.y);
        a2.x = fmaf(h0v.y, w01.z, a2.x); a2.y = fmaf(h0v.y, w01.w, a2.y);
        a2.x = fmaf(h1v.x, w23.x, a2.x); a2.y = fmaf(h1v.x, w23.y, a2.y);
        a2.x = fmaf(h1v.y, w23.z, a2.x); a2.y = fmaf(h1v.y, w23.w, a2.y);
      }
      float* wr = &zred[(ksu * 128 + bl) * 4];
      wr[0] = a2.x; wr[1] = a2.y;
    }
    __syncthreads();
    if (tid < 256) {
      int b = tid >> 1, jj = tid & 1;
      float s2 = 0.0f;
#pragma unroll
      for (int k = 0; k < 8; ++k) s2 += zred[(k * 128 + b) * 4 + jj];
      w2d[(size_t)b * 512 + 2 * g + jj] = s2;
    }
    gridbar(cnt, tgt, tid);

    // ================= score =================
    {
      float4 u0 = ld4(w2d + (size_t)sb * 512 + ln * 8);
      float4 u1 = ld4(w2d + (size_t)sb * 512 + ln * 8 + 4);
      float2 ddp = d2r[sb];
      float rdp = rcp_f(ddp.x + ddp.y);
      float dacc = 0.0f;
      for (int r = 0; r < 8; ++r) {
        int t = t0 + wv * 8 + r;
        const float* row = w1e + (((size_t)sb * 256 + t) << 9) + ln * 8;
        float4 x0 = ld4(row), x1 = ld4(row + 4);
        float a;
        a = tanh_f(x0.x + u0.x) * v0.x;
        a = fmaf(tanh_f(x0.y + u0.y), v0.y, a);
        a = fmaf(tanh_f(x0.z + u0.z), v0.z, a);
        a = fmaf(tanh_f(x0.w + u0.w), v0.w, a);
        a = fmaf(tanh_f(x1.x + u1.x), v1.x, a);
        a = fmaf(tanh_f(x1.y + u1.y), v1.y, a);
        a = fmaf(tanh_f(x1.z + u1.z), v1.z, a);
        a = fmaf(tanh_f(x1.w + u1.w), v1.w, a);
#pragma unroll
        for (int m = 32; m > 0; m >>= 1) a += __shfl_xor(a, m, 64);
        if (ln == 0) {
          int slot = ((t >> 1) * 128 + sb) * 2 + (t & 1);
          if (s > 0) out[(size_t)sb * 65536 + (size_t)(s - 1) * 256 + t] = ep[slot] * rdp;
          float ev = __expf(a);
          ep[slot] = ev;
          dacc += ev;
        }
      }
      if (ln == 0) dred[wv] = dacc;
      __syncthreads();
      if (tid == 0) {
        float sd = 0.0f;
#pragma unroll
        for (int k = 0; k < 16; ++k) sd += dred[k];
        d2w[sb * 2 + (g & 1)] = sd;
      }
    }
    gridbar(cnt, tgt, tid);
  }

  // ---- final: out row 255 using d(255) (buffer 1) ----
  {
    const float2* d2f = (const float2*)(d2 + 256);
    float2 ddp = d2f[sb];
    float rdp = rcp_f(ddp.x + ddp.y);
    if (tid < 128) {
      int t = t0 + tid;
      int slot = ((t >> 1) * 128 + sb) * 2 + (t & 1);
      out[(size_t)sb * 65536 + 255ull * 256 + t] = ep[slot] * rdp;
    }
  }
}

extern "C" void kernel_launch(void* const* d_in, const int* in_sizes, int n_in,
                              void* d_out, int out_size, void* d_ws, size_t ws_size,
                              hipStream_t stream) {
  const float* enc  = (const float*)d_in[0];
  const float* h0   = (const float*)d_in[1];
  const float* c0   = (const float*)d_in[2];
  const float* W1   = (const float*)d_in[3];
  const float* W2   = (const float*)d_in[4];
  const float* V    = (const float*)d_in[5];
  const float* Wk   = (const float*)d_in[6];
  const float* Wr   = (const float*)d_in[7];
  const float* bias = (const float*)d_in[8];
  float* out = (float*)d_out;
  float* ws = (float*)d_ws;

  float* w1e    = ws + W1E_OFF;
  float* Wpack  = ws + WPACK_OFF;
  float* W2pack = ws + W2PACK_OFF;
  float* hp     = ws + HP_OFF;
  float* ep     = ws + EP_OFF;
  float* w2d    = ws + W2D_OFF;
  float* d2     = ws + D2_OFF;
  unsigned* cnt = (unsigned*)(ws + CNT_OFF);

  pack_kernel<<<256, 256, 0, stream>>>(Wk, Wr, W2, Wpack, W2pack, cnt);
  w1e_kernel<<<dim3(512, 8), 256, 0, stream>>>(enc, W1, w1e);
  decoder_persistent<<<256, 1024, 0, stream>>>(w1e, Wpack, W2pack, V, bias, h0, c0,
                                               hp, ep, w2d, d2, cnt, out);
}

// Round 3
// 9359.789 us; speedup vs baseline: 10.9150x; 10.9150x over previous
//
#include <hip/hip_runtime.h>
#include <hip/hip_bf16.h>
#include <cstddef>

#define B_ 128
#define T_ 256
#define H_ 512
#define H4_ 2048

__device__ __forceinline__ float rcp_f(float x) { return __builtin_amdgcn_rcpf(x); }
__device__ __forceinline__ float sigf(float x) { return rcp_f(1.0f + __expf(-x)); }
__device__ __forceinline__ float tanh_f(float x) {
  float p = __expf(x + x);
  return fmaf(-2.0f, rcp_f(1.0f + p), 1.0f);
}
__device__ __forceinline__ float4 ld4(const float* p) { return *reinterpret_cast<const float4*>(p); }
__device__ __forceinline__ void st4(float* p, float4 v) { *reinterpret_cast<float4*>(p) = v; }
__device__ __forceinline__ void fma4(float4& a, float s, float4 w) {
  a.x = fmaf(s, w.x, a.x); a.y = fmaf(s, w.y, a.y);
  a.z = fmaf(s, w.z, a.z); a.w = fmaf(s, w.w, a.w);
}

// ---- agent-scope (LLC-coherent, L1/L2-bypassing) accessors for mutable shared data ----
__device__ __forceinline__ float ald1(const float* p) {
  return __hip_atomic_load(p, __ATOMIC_RELAXED, __HIP_MEMORY_SCOPE_AGENT);
}
__device__ __forceinline__ void ast1(float* p, float v) {
  __hip_atomic_store(p, v, __ATOMIC_RELAXED, __HIP_MEMORY_SCOPE_AGENT);
}
__device__ __forceinline__ float2 ald2(const float* p) {
  unsigned long long v = __hip_atomic_load((const unsigned long long*)p,
                                           __ATOMIC_RELAXED, __HIP_MEMORY_SCOPE_AGENT);
  union { unsigned long long u; float2 f; } c; c.u = v; return c.f;
}

// ---------------- workspace layout (float offsets) ----------------
#define W1E_OFF   0ull          // 16777216
#define WPACK_OFF 16777216ull   // 1572864  Wpack[g][k=768][c=8]
#define HP_OFF    18350080ull   // 131072   htr[2][256 k2][128 b][2]
#define HROW_OFF  18481152ull   // 65536    hrow[128 b][512]
#define EP_OFF    18546688ull   // 32768    etr[128 t2][128 b][2]
#define W2D_OFF   18579456ull   // 65536    w2d[128 b][512]
#define D2_OFF    18644992ull   // 512      d2[2][128 b][2]
#define CNT_OFF   18645504ull   // 1024 uints

// ---------------- w1e = enc[32768,512] @ W1[512,512] ----------------
__global__ __launch_bounds__(256) void w1e_kernel(const float* __restrict__ A,
                                                  const float* __restrict__ Bw,
                                                  float* __restrict__ C) {
  __shared__ float As[32][68];
  __shared__ float Bs[32][68];
  const int i0 = blockIdx.x * 64;
  const int j0 = blockIdx.y * 64;
  const int tx = threadIdx.x & 15, ty = threadIdx.x >> 4;
  float4 acc0 = make_float4(0,0,0,0), acc1 = acc0, acc2 = acc0, acc3 = acc0;
  for (int k0 = 0; k0 < H_; k0 += 32) {
#pragma unroll
    for (int q = 0; q < 2; q++) {
      int idx = q * 256 + threadIdx.x;
      int ai = idx >> 3, ak = (idx & 7) << 2;
      float4 av = ld4(A + (size_t)(i0 + ai) * H_ + k0 + ak);
      As[ak][ai] = av.x; As[ak + 1][ai] = av.y; As[ak + 2][ai] = av.z; As[ak + 3][ai] = av.w;
      int bk = idx >> 4, bj = (idx & 15) << 2;
      st4(&Bs[bk][bj], ld4(Bw + (size_t)(k0 + bk) * H_ + j0 + bj));
    }
    __syncthreads();
#pragma unroll
    for (int kk = 0; kk < 32; kk++) {
      float4 a = ld4(&As[kk][ty << 2]);
      float4 bv = ld4(&Bs[kk][tx << 2]);
      fma4(acc0, a.x, bv); fma4(acc1, a.y, bv); fma4(acc2, a.z, bv); fma4(acc3, a.w, bv);
    }
    __syncthreads();
  }
  size_t base = (size_t)(i0 + (ty << 2)) * H_ + j0 + (tx << 2);
  st4(&C[base], acc0); st4(&C[base + H_], acc1);
  st4(&C[base + 2 * H_], acc2); st4(&C[base + 3 * H_], acc3);
}

// ---------------- pack Wk/Wr per-WG contiguous + zero barrier counters ----------------
__global__ __launch_bounds__(256) void pack_kernel(const float* __restrict__ Wk,
                                                   const float* __restrict__ Wr,
                                                   float* __restrict__ Wpack,
                                                   unsigned* __restrict__ cnt) {
  const int g = blockIdx.x, tid = threadIdx.x;
#pragma unroll
  for (int it = 0; it < 24; ++it) {
    int idx = it * 256 + tid;            // 0..6143
    int k = idx >> 3, c = idx & 7;       // c = gate*2 + jj
    int col = (c >> 1) * 512 + 2 * g + (c & 1);
    float v = (k < 256) ? Wk[(size_t)k * H4_ + col] : Wr[(size_t)(k - 256) * H4_ + col];
    Wpack[((size_t)g * 768 + k) * 8 + c] = v;
  }
  if (g == 0) {
#pragma unroll
    for (int i = 0; i < 4; ++i) cnt[i * 256 + tid] = 0u;
  }
}

// ---------------- low-contention two-level grid barrier (no fences) ----------------
// cnt layout: [0..511]  32 L1 counters at stride 16 (64B)
//             [512]     L2 counter
//             [768..895] 8 release flags at stride 16
__device__ __forceinline__ void gridbar(unsigned* cnt, unsigned& phase, int tid, int wg) {
  asm volatile("s_waitcnt vmcnt(0)" ::: "memory");  // every wave: own stores visible at LLC
  __syncthreads();
  if (tid == 0) {
    unsigned r1 = __hip_atomic_fetch_add(&cnt[(wg & 31) * 16], 1u,
                                         __ATOMIC_RELAXED, __HIP_MEMORY_SCOPE_AGENT);
    if (r1 == phase * 8u + 7u) {  // last of this group's 8 WGs
      unsigned r2 = __hip_atomic_fetch_add(&cnt[512], 1u,
                                           __ATOMIC_RELAXED, __HIP_MEMORY_SCOPE_AGENT);
      if (r2 == phase * 32u + 31u) {  // global last -> release
#pragma unroll
        for (int i = 0; i < 8; ++i)
          __hip_atomic_store(&cnt[768 + i * 16], phase + 1u,
                             __ATOMIC_RELAXED, __HIP_MEMORY_SCOPE_AGENT);
      }
    }
    const unsigned* rel = &cnt[768 + (wg >> 5) * 16];
    while (__hip_atomic_load(rel, __ATOMIC_RELAXED, __HIP_MEMORY_SCOPE_AGENT) <= phase)
      __builtin_amdgcn_s_sleep(4);
  }
  __syncthreads();
  ++phase;
}

// ---------------- persistent decoder: 256 WGs x 1024 thr, 1 WG/CU ----------------
__global__ __launch_bounds__(1024, 4) void decoder_persistent(
    const float* __restrict__ w1e, const float* __restrict__ Wpack,
    const float* __restrict__ W2, const float* __restrict__ Vv,
    const float* __restrict__ bias, const float* __restrict__ h0,
    const float* __restrict__ c0,
    float* __restrict__ htr,   // [2][256][128][2]
    float* __restrict__ hrow,  // [128][512]
    float* __restrict__ etr,   // [128][128][2]
    float* __restrict__ w2dA,  // [128][512]
    float* __restrict__ d2,    // [2][128][2]
    unsigned* __restrict__ cnt,
    float* __restrict__ out) {
  // 84KB LDS: forces 1 WG/CU -> all 256 WGs co-resident (barrier deadlock-free)
  __shared__ float smem[21504];
  float* zred     = smem;            // gates: [8][128][12]; w2d: [16][256]
  float* zfin     = smem + 12288;    // [128][8]
  float* c_lds    = smem + 13312;    // [128][2]
  float* bias_lds = smem + 13568;    // [8]
  float* dred     = smem + 13576;    // [16]

  const int g = blockIdx.x;
  const int tid = threadIdx.x;
  const int bl = tid & 127;
  const int ksu = __builtin_amdgcn_readfirstlane(tid >> 7);  // 0..7 k-split
  const int wv = tid >> 6, ln = tid & 63;
  const int sb = g >> 1;            // batch row (score & w2d phases)
  const int t0 = (g & 1) << 7;      // t half / col half
  unsigned phase = 0;
  float epv[8];                     // lane0-of-wave: this WG's e values (prev step)

  // ---- init ----
  if (tid < 256) {
    int b = tid >> 1, jj = tid & 1;
    c_lds[b * 2 + jj] = c0[(size_t)b * H_ + 2 * g + jj];
    ast1(htr + 65536 + ((size_t)g * 128 + b) * 2 + jj, h0[(size_t)b * H_ + 2 * g + jj]);
    if (g == 0) ast1(d2 + 256 + tid, 0.5f);   // d(-1): pair sums to 1
  }
  if (tid < 8) bias_lds[tid] = bias[(tid >> 1) * 512 + 2 * g + (tid & 1)];
  if (g < 128) ast1(etr + g * 256 + tid, 1.0f);   // e(-1) = 1
  gridbar(cnt, phase, tid, g);

  const float4 v0 = ld4(Vv + (ln << 3));
  const float4 v1 = ld4(Vv + (ln << 3) + 4);

  for (int s = 0; s < 256; ++s) {
    const float* hin = htr + ((s + 1) & 1) * 65536;
    float* hout = htr + (s & 1) * 65536;
    const float* dPrev = d2 + ((s + 1) & 1) * 256;
    float* dCur = d2 + (s & 1) * 256;

    // ================= gates =================
    {
      float2 dd = ald2(dPrev + bl * 2);
      float rd = rcp_f(dd.x + dd.y);
      float4 accA = make_float4(0,0,0,0), accB = accA;
#pragma unroll 4
      for (int j = 0; j < 8; ++j) {          // e-part: k in [0,256)
        int kb = ksu * 4 + j * 32;
        float2 i0 = ald2(etr + (kb >> 1) * 256 + bl * 2);
        float2 i1 = ald2(etr + (kb >> 1) * 256 + 256 + bl * 2);
        const float* wp = Wpack + (((size_t)g * 768 + kb) << 3);
        float4 wa0 = ld4(wp),      wb0 = ld4(wp + 4);
        float4 wa1 = ld4(wp + 8),  wb1 = ld4(wp + 12);
        float4 wa2 = ld4(wp + 16), wb2 = ld4(wp + 20);
        float4 wa3 = ld4(wp + 24), wb3 = ld4(wp + 28);
        fma4(accA, i0.x, wa0); fma4(accB, i0.x, wb0);
        fma4(accA, i0.y, wa1); fma4(accB, i0.y, wb1);
        fma4(accA, i1.x, wa2); fma4(accB, i1.x, wb2);
        fma4(accA, i1.y, wa3); fma4(accB, i1.y, wb3);
      }
      accA.x *= rd; accA.y *= rd; accA.z *= rd; accA.w *= rd;
      accB.x *= rd; accB.y *= rd; accB.z *= rd; accB.w *= rd;
#pragma unroll 4
      for (int j = 0; j < 16; ++j) {         // h-part: k in [0,512)
        int kb = ksu * 4 + j * 32;
        float2 i0 = ald2(hin + (kb >> 1) * 256 + bl * 2);
        float2 i1 = ald2(hin + (kb >> 1) * 256 + 256 + bl * 2);
        const float* wp = Wpack + (((size_t)g * 768 + 256 + kb) << 3);
        float4 wa0 = ld4(wp),      wb0 = ld4(wp + 4);
        float4 wa1 = ld4(wp + 8),  wb1 = ld4(wp + 12);
        float4 wa2 = ld4(wp + 16), wb2 = ld4(wp + 20);
        float4 wa3 = ld4(wp + 24), wb3 = ld4(wp + 28);
        fma4(accA, i0.x, wa0); fma4(accB, i0.x, wb0);
        fma4(accA, i0.y, wa1); fma4(accB, i0.y, wb1);
        fma4(accA, i1.x, wa2); fma4(accB, i1.x, wb2);
        fma4(accA, i1.y, wa3); fma4(accB, i1.y, wb3);
      }
      float* zr = &zred[(ksu * 128 + bl) * 12];
      st4(zr, accA); st4(zr + 4, accB);
    }
    __syncthreads();
    {  // k-split reduce: 1024 thr = 128 b x 8 c
      int b = tid >> 3, cc = tid & 7;
      float zsum = bias_lds[cc];
#pragma unroll
      for (int k2 = 0; k2 < 8; ++k2) zsum += zred[(k2 * 128 + b) * 12 + cc];
      zfin[b * 8 + cc] = zsum;
    }
    __syncthreads();
    if (tid < 256) {  // LSTM epilogue: this WG's 2 h-cols
      int b = tid >> 1, jj = tid & 1;
      float zi = zfin[b * 8 + 0 + jj], zf = zfin[b * 8 + 2 + jj];
      float zg = zfin[b * 8 + 4 + jj], zo = zfin[b * 8 + 6 + jj];
      float cv = c_lds[b * 2 + jj];
      float cn = sigf(zf) * cv + sigf(zi) * tanh_f(zg);
      float hn = sigf(zo) * tanh_f(cn);
      c_lds[b * 2 + jj] = cn;
      ast1(hout + ((size_t)g * 128 + b) * 2 + jj, hn);
      ast1(hrow + (size_t)b * 512 + 2 * g + jj, hn);
    }
    gridbar(cnt, phase, tid, g);

    // ================= w2d (batch-split): w2d[sb, half] = h[sb,:] @ W2[:, half] =======
    {
      const int ci = t0 + (t0 ? 256 - 128 : 0);  // col base: (g&1)*256
      const int colb = ((g & 1) << 8) + (ln << 2);
      (void)ci;
      float4 acc = make_float4(0,0,0,0);
      const float* hb = hrow + (size_t)sb * 512 + (wv << 5);
#pragma unroll 8
      for (int kk = 0; kk < 32; ++kk) {
        float hk = ald1(hb + kk);
        float4 wr2 = ld4(W2 + (size_t)((wv << 5) + kk) * 512 + colb);
        fma4(acc, hk, wr2);
      }
      st4(&zred[(wv << 8) + (ln << 2)], acc);
    }
    __syncthreads();
    if (tid < 256) {
      float sum = 0.0f;
#pragma unroll
      for (int w = 0; w < 16; ++w) sum += zred[(w << 8) + tid];
      ast1(w2dA + (size_t)sb * 512 + ((g & 1) << 8) + tid, sum);
    }
    gridbar(cnt, phase, tid, g);

    // ================= score =================
    {
      const float* wrow = w2dA + (size_t)sb * 512 + (ln << 3);
      float2 a0 = ald2(wrow), a1 = ald2(wrow + 2), a2 = ald2(wrow + 4), a3 = ald2(wrow + 6);
      float4 u0 = make_float4(a0.x, a0.y, a1.x, a1.y);
      float4 u1 = make_float4(a2.x, a2.y, a3.x, a3.y);
      float2 ddp = ald2(dPrev + sb * 2);
      float rdp = rcp_f(ddp.x + ddp.y);
      float dacc = 0.0f;
#pragma unroll
      for (int r = 0; r < 8; ++r) {
        int t = t0 + (wv << 3) + r;
        const float* row = w1e + (((size_t)sb * 256 + t) << 9) + (ln << 3);
        float4 x0 = ld4(row), x1 = ld4(row + 4);
        float a;
        a = tanh_f(x0.x + u0.x) * v0.x;
        a = fmaf(tanh_f(x0.y + u0.y), v0.y, a);
        a = fmaf(tanh_f(x0.z + u0.z), v0.z, a);
        a = fmaf(tanh_f(x0.w + u0.w), v0.w, a);
        a = fmaf(tanh_f(x1.x + u1.x), v1.x, a);
        a = fmaf(tanh_f(x1.y + u1.y), v1.y, a);
        a = fmaf(tanh_f(x1.z + u1.z), v1.z, a);
        a = fmaf(tanh_f(x1.w + u1.w), v1.w, a);
#pragma unroll
        for (int m = 32; m > 0; m >>= 1) a += __shfl_xor(a, m, 64);
        if (ln == 0) {
          if (s > 0) out[(size_t)sb * 65536 + (size_t)(s - 1) * 256 + t] = epv[r] * rdp;
          float ev = __expf(a);
          epv[r] = ev;
          ast1(etr + (((t >> 1) << 7) + sb) * 2 + (t & 1), ev);
          dacc += ev;
        }
      }
      if (ln == 0) dred[wv] = dacc;
    }
    __syncthreads();
    if (tid == 0) {
      float sd = 0.0f;
#pragma unroll
      for (int k = 0; k < 16; ++k) sd += dred[k];
      ast1(dCur + sb * 2 + (g & 1), sd);
    }
    gridbar(cnt, phase, tid, g);
  }

  // ---- final: out row 255 (e of step 255 still in regs; d(255) in buffer 1) ----
  {
    float2 ddf = ald2(d2 + 256 + sb * 2);
    float rdf = rcp_f(ddf.x + ddf.y);
    if (ln == 0) {
#pragma unroll
      for (int r = 0; r < 8; ++r) {
        int t = t0 + (wv << 3) + r;
        out[(size_t)sb * 65536 + 255ull * 256 + t] = epv[r] * rdf;
      }
    }
  }
}

extern "C" void kernel_launch(void* const* d_in, const int* in_sizes, int n_in,
                              void* d_out, int out_size, void* d_ws, size_t ws_size,
                              hipStream_t stream) {
  const float* enc  = (const float*)d_in[0];
  const float* h0   = (const float*)d_in[1];
  const float* c0   = (const float*)d_in[2];
  const float* W1   = (const float*)d_in[3];
  const float* W2   = (const float*)d_in[4];
  const float* V    = (const float*)d_in[5];
  const float* Wk   = (const float*)d_in[6];
  const float* Wr   = (const float*)d_in[7];
  const float* bias = (const float*)d_in[8];
  float* out = (float*)d_out;
  float* ws = (float*)d_ws;

  float* w1e    = ws + W1E_OFF;
  float* Wpack  = ws + WPACK_OFF;
  float* htr    = ws + HP_OFF;
  float* hrow   = ws + HROW_OFF;
  float* etr    = ws + EP_OFF;
  float* w2dA   = ws + W2D_OFF;
  float* d2     = ws + D2_OFF;
  unsigned* cnt = (unsigned*)(ws + CNT_OFF);

  pack_kernel<<<256, 256, 0, stream>>>(Wk, Wr, Wpack, cnt);
  w1e_kernel<<<dim3(512, 8), 256, 0, stream>>>(enc, W1, w1e);
  decoder_persistent<<<256, 1024, 0, stream>>>(w1e, Wpack, W2, V, bias, h0, c0,
                                               htr, hrow, etr, w2dA, d2, cnt, out);
}